// Round 2
// baseline (1655.018 us; speedup 1.0000x reference)
//
#include <hip/hip_runtime.h>
#include <hip/hip_bf16.h>

typedef __hip_bfloat16 bf16;

#define NN 16384
#define NB 64
#define NE_TOT (NN*8 + NN)   // 147456 edges incl. self-loops
#define CW 128

static_assert(NE_TOT == 147456, "edge count");

__device__ __forceinline__ float b2f(bf16 x){ return __bfloat162float(x); }
__device__ __forceinline__ bf16  f2b(float x){ return __float2bfloat16(x); }
__device__ __forceinline__ float lrelu(float x){ return x > 0.f ? x : 0.2f*x; }
__device__ __forceinline__ float gelu_f(float x){ return 0.5f*x*(1.f + erff(x*0.70710678118654752f)); }

// ---------------- input dtype detection ----------------
// feats is one-hot (values exactly 0.0/1.0). If inputs are f32, the low
// half-word of every element is 0x0000, so 0x3F80 never appears at an even
// u16 index. If bf16, ~256 of the first 2048 even slots are 0x3F80.
__global__ void k_detect(const unsigned short* __restrict__ f, int* __restrict__ flag){
  __shared__ int cnt;
  if(threadIdx.x == 0) cnt = 0;
  __syncthreads();
  int c = 0;
  for(int i = threadIdx.x; i < 2048; i += 256)
    if(f[2*i] == 0x3F80) c++;
  atomicAdd(&cnt, c);
  __syncthreads();
  if(threadIdx.x == 0) *flag = (cnt > 0) ? 0 : 1;   // 0 = bf16 inputs, 1 = f32 inputs
}

// one launch converts all 32 float tensors to bf16 (or copies if already bf16)
struct ConvArgs { const void* in[32]; bf16* out[32]; int n[32]; };
__global__ __launch_bounds__(256) void k_conv_all(ConvArgs a, const int* __restrict__ flag){
  int which = blockIdx.y;
  int t = blockIdx.x*256 + threadIdx.x;
  int n = a.n[which];
  if(t >= n) return;
  if(*flag) a.out[which][t] = f2b(((const float*)a.in[which])[t]);
  else      a.out[which][t] = ((const bf16*)a.in[which])[t];
}

// ---------------- CSR build (by dst) ----------------
__global__ void k_zero2(int* __restrict__ a, int* __restrict__ b, int n){
  int i = blockIdx.x*blockDim.x + threadIdx.x;
  if(i < n){ a[i] = 0; b[i] = 0; }
}

__global__ void k_hist(const int* __restrict__ dst, int* __restrict__ deg, int ne){
  int e = blockIdx.x*blockDim.x + threadIdx.x;
  if(e < ne) atomicAdd(&deg[dst[e]], 1);
}

__global__ void k_scan(const int* __restrict__ deg, int* __restrict__ off){
  __shared__ int s[256];
  int t = threadIdx.x;
  const int chunk = NN/256;
  int base = t*chunk;
  int sum = 0;
  for(int i=0;i<chunk;i++) sum += deg[base+i];
  s[t] = sum; __syncthreads();
  for(int o=1;o<256;o<<=1){
    int v = (t >= o) ? s[t-o] : 0;
    __syncthreads();
    s[t] += v;
    __syncthreads();
  }
  int run = (t == 0) ? 0 : s[t-1];
  for(int i=0;i<chunk;i++){ off[base+i] = run; run += deg[base+i]; }
  if(t == 255) off[NN] = run;
}

__global__ void k_scatter(const int* __restrict__ src, const int* __restrict__ dst,
                          const int* __restrict__ off, int* __restrict__ cursor,
                          int* __restrict__ csr_src, int ne){
  int e = blockIdx.x*blockDim.x + threadIdx.x;
  if(e < ne){
    int d = dst[e];
    int p = off[d] + atomicAdd(&cursor[d], 1);
    csr_src[p] = src[e];
  }
}

// expand csr_dst from off (needed by edge-parallel logits kernel)
__global__ void k_fill_dst(const int* __restrict__ off, int* __restrict__ csr_dst){
  int n = blockIdx.x*blockDim.x + threadIdx.x;
  if(n < NN){
    int p1 = off[n+1];
    for(int p = off[n]; p < p1; p++) csr_dst[p] = n;
  }
}

// ---------------- up projection (K=8, one block/node) ----------------
__global__ __launch_bounds__(128) void k_up(const bf16* __restrict__ feats,
    const bf16* __restrict__ Ws, const bf16* __restrict__ bs,
    const bf16* __restrict__ Wd, const bf16* __restrict__ bd,
    bf16* __restrict__ el, bf16* __restrict__ er){
  int n = blockIdx.x, c = threadIdx.x;
  __shared__ float f[8];
  if(c < 8) f[c] = b2f(feats[n*8 + c]);
  __syncthreads();
  float a = b2f(bs[c]), b = b2f(bd[c]);
  #pragma unroll
  for(int k=0;k<8;k++){
    float fv = f[k];
    a += fv*b2f(Ws[k*CW + c]);
    b += fv*b2f(Wd[k*CW + c]);
  }
  el[(size_t)n*CW + c] = f2b(a);
  er[(size_t)n*CW + c] = f2b(b);
}

// ---------------- generic tiled GEMM: C[M,J] = act(A[M,K] @ W[K,J] + bias) ----------------
template<int ACT>
__global__ __launch_bounds__(256) void k_gemm(const bf16* __restrict__ A, int lda,
    const bf16* __restrict__ W, const bf16* __restrict__ bias,
    bf16* __restrict__ Cmat, int ldc, int M, int K, int J){
  __shared__ float As[16][65];
  __shared__ float Bs[16][65];
  int tid = threadIdx.x;
  int tx = tid & 15, ty = tid >> 4;
  int bm = blockIdx.y*64, bn = blockIdx.x*64;
  float acc[4][4] = {};
  for(int kt=0; kt<K; kt+=16){
    {
      int r = tid >> 2;
      int c = (tid & 3)*4;
      const bf16* ap = A + (size_t)(bm + r)*lda + kt + c;
      As[c+0][r] = b2f(ap[0]); As[c+1][r] = b2f(ap[1]);
      As[c+2][r] = b2f(ap[2]); As[c+3][r] = b2f(ap[3]);
    }
    {
      int r = tid >> 4;
      int c = (tid & 15)*4;
      const bf16* wp = W + (size_t)(kt + r)*J + bn + c;
      Bs[r][c+0] = b2f(wp[0]); Bs[r][c+1] = b2f(wp[1]);
      Bs[r][c+2] = b2f(wp[2]); Bs[r][c+3] = b2f(wp[3]);
    }
    __syncthreads();
    #pragma unroll
    for(int k=0;k<16;k++){
      float a[4], b[4];
      #pragma unroll
      for(int i=0;i<4;i++){ a[i] = As[k][ty*4+i]; b[i] = Bs[k][tx*4+i]; }
      #pragma unroll
      for(int i=0;i<4;i++)
        #pragma unroll
        for(int j=0;j<4;j++) acc[i][j] += a[i]*b[j];
    }
    __syncthreads();
  }
  #pragma unroll
  for(int i=0;i<4;i++){
    int m = bm + ty*4 + i;
    #pragma unroll
    for(int j=0;j<4;j++){
      int n = bn + tx*4 + j;
      float v = acc[i][j] + b2f(bias[n]);
      if(ACT == 1) v = gelu_f(v);
      Cmat[(size_t)m*ldc + n] = f2b(v);
    }
  }
}

// ---------------- edge logits: one wave per CSR position ----------------
__global__ __launch_bounds__(256) void k_logits(const bf16* __restrict__ el, const bf16* __restrict__ er,
    const bf16* __restrict__ attn, const int* __restrict__ csr_src, const int* __restrict__ csr_dst,
    float* __restrict__ logits, int H){
  int pos = blockIdx.x*4 + (threadIdx.x >> 6);
  int lane = threadIdx.x & 63;
  if(pos >= NE_TOT) return;
  int s = csr_src[pos], d = csr_dst[pos];
  size_t rs = (size_t)H*CW;
  for(int h=0; h<H; h++){
    int b = h*CW;
    float e0 = lrelu(b2f(el[s*rs + b + lane])      + b2f(er[d*rs + b + lane]));
    float e1 = lrelu(b2f(el[s*rs + b + lane + 64]) + b2f(er[d*rs + b + lane + 64]));
    float p = e0*b2f(attn[b + lane]) + e1*b2f(attn[b + lane + 64]);
    #pragma unroll
    for(int o=32;o;o>>=1) p += __shfl_down(p, o, 64);
    if(lane == 0) logits[(size_t)pos*H + h] = p;
  }
}

// ---------------- per-(node,head) edge softmax (in place) ----------------
__global__ void k_soft(const int* __restrict__ off, float* __restrict__ logits, int H){
  int t = blockIdx.x*blockDim.x + threadIdx.x;
  int n = t / H, h = t - n*H;
  if(n >= NN) return;
  int p0 = off[n], p1 = off[n+1];
  float m = -1e30f;
  for(int p=p0;p<p1;p++) m = fmaxf(m, logits[(size_t)p*H + h]);
  float z = 0.f;
  for(int p=p0;p<p1;p++) z += expf(logits[(size_t)p*H + h] - m);
  float rz = 1.f/z;
  for(int p=p0;p<p1;p++) logits[(size_t)p*H + h] = expf(logits[(size_t)p*H + h] - m)*rz;
}

// ---------------- aggregate: one wave per (node, head) ----------------
__global__ __launch_bounds__(256) void k_aggr(const int* __restrict__ off, const int* __restrict__ csr_src,
    const float* __restrict__ acoef, const bf16* __restrict__ el, bf16* __restrict__ out, int H){
  int w = blockIdx.x*4 + (threadIdx.x >> 6);
  int lane = threadIdx.x & 63;
  int n = w / H, h = w - n*H;
  if(n >= NN) return;
  size_t rs = (size_t)H*CW;
  int b = h*CW;
  float a0 = 0.f, a1 = 0.f;
  int p1 = off[n+1];
  for(int p=off[n]; p<p1; p++){
    float a = acoef[(size_t)p*H + h];
    int s = csr_src[p];
    a0 += a*b2f(el[s*rs + b + lane]);
    a1 += a*b2f(el[s*rs + b + lane + 64]);
  }
  out[n*rs + b + lane]      = f2b(a0);
  out[n*rs + b + lane + 64] = f2b(a1);
}

// ---------------- layernorm over last dim (128), one wave per row, in place ----------------
__global__ __launch_bounds__(256) void k_ln(bf16* __restrict__ y, const bf16* __restrict__ g,
                                            const bf16* __restrict__ bb, int nrows){
  int row = blockIdx.x*4 + (threadIdx.x >> 6);
  int lane = threadIdx.x & 63;
  if(row >= nrows) return;
  bf16* yr = y + (size_t)row*CW;
  float v0 = b2f(yr[lane]), v1 = b2f(yr[lane+64]);
  float s = v0 + v1;
  #pragma unroll
  for(int o=32;o;o>>=1) s += __shfl_xor(s, o, 64);
  float mu = s*(1.f/128.f);
  float d0 = v0 - mu, d1 = v1 - mu;
  float q = d0*d0 + d1*d1;
  #pragma unroll
  for(int o=32;o;o>>=1) q += __shfl_xor(q, o, 64);
  float r = rsqrtf(q*(1.f/128.f) + 1e-5f);
  yr[lane]    = f2b(d0*r*b2f(g[lane])    + b2f(bb[lane]));
  yr[lane+64] = f2b(d1*r*b2f(g[lane+64]) + b2f(bb[lane+64]));
}

// ---------------- gate: one wave per node, dot over 1024 ----------------
__global__ __launch_bounds__(256) void k_gate(const bf16* __restrict__ y2, const bf16* __restrict__ gW,
                                              const bf16* __restrict__ gb, float* __restrict__ gate){
  int n = blockIdx.x*4 + (threadIdx.x >> 6);
  int lane = threadIdx.x & 63;
  if(n >= NN) return;
  const bf16* yr = y2 + (size_t)n*1024;
  float p = 0.f;
  #pragma unroll
  for(int j=0;j<16;j++) p += b2f(yr[lane + j*64])*b2f(gW[lane + j*64]);
  #pragma unroll
  for(int o=32;o;o>>=1) p += __shfl_down(p, o, 64);
  if(lane == 0) gate[n] = p + b2f(gb[0]);
}

// ---------------- gated pooling + tanh: one block per graph ----------------
__global__ __launch_bounds__(256) void k_pool(const float* __restrict__ gate, const bf16* __restrict__ y2,
                                              void* __restrict__ outv, const int* __restrict__ flag){
  int g = blockIdx.x, t = threadIdx.x;
  __shared__ float red[256];
  __shared__ float w[256];
  float gv = gate[g*256 + t];
  red[t] = gv; __syncthreads();
  for(int o=128;o;o>>=1){ if(t < o) red[t] = fmaxf(red[t], red[t+o]); __syncthreads(); }
  float m = red[0]; __syncthreads();
  float e = expf(gv - m);
  red[t] = e; __syncthreads();
  for(int o=128;o;o>>=1){ if(t < o) red[t] += red[t+o]; __syncthreads(); }
  float z = red[0]; __syncthreads();
  w[t] = e / z; __syncthreads();
  float acc[4] = {0.f,0.f,0.f,0.f};
  const bf16* base = y2 + (size_t)g*256*1024;
  for(int i=0;i<256;i++){
    float wi = w[i];
    #pragma unroll
    for(int jj=0;jj<4;jj++) acc[jj] += wi*b2f(base[(size_t)i*1024 + jj*256 + t]);
  }
  bool f32o = (*flag != 0);
  #pragma unroll
  for(int jj=0;jj<4;jj++){
    float v = tanhf(acc[jj]);
    size_t idx = (size_t)g*1024 + jj*256 + t;
    if(f32o) ((float*)outv)[idx] = v;
    else     ((bf16*)outv)[idx] = f2b(v);
  }
}

extern "C" void kernel_launch(void* const* d_in, const int* in_sizes, int n_in,
                              void* d_out, int out_size, void* d_ws, size_t ws_size,
                              hipStream_t stream){
  const int*  src    = (const int*)d_in[1];
  const int*  dst    = (const int*)d_in[2];

  char* wsb = (char*)d_ws;
  size_t o = 0;
  auto take = [&](size_t bytes)->char*{
    char* p = wsb + o; o = (o + bytes + 255) & ~(size_t)255; return p;
  };
  int*   flag    = (int*)take(4);
  float* logits  = (float*)take((size_t)NE_TOT*8*sizeof(float));   // also acoef (in-place)
  float* gate    = (float*)take((size_t)NN*sizeof(float));
  int* deg       = (int*)take((size_t)NN*4);
  int* cursor    = (int*)take((size_t)NN*4);
  int* off       = (int*)take((size_t)(NN+1)*4);
  int* csr_src   = (int*)take((size_t)NE_TOT*4);
  int* csr_dst   = (int*)take((size_t)NE_TOT*4);

  // converted-to-bf16 copies of all 32 float tensors
  ConvArgs ca;
  const int fidx[32] = {0, 4,5,6,7,8, 9,10,11,12,13, 14,15,16,17,18,19,20,21,
                        22,23,24,25,26, 27,28,29,30,31,32, 33,34};
  bf16* cp[32];
  int maxn = 0;
  for(int i=0;i<32;i++){
    int n = in_sizes[fidx[i]];
    cp[i] = (bf16*)take((size_t)n*2);
    ca.in[i] = d_in[fidx[i]]; ca.out[i] = cp[i]; ca.n[i] = n;
    if(n > maxn) maxn = n;
  }
  const bf16* cfeats  = cp[0];
  const bf16* up_Ws   = cp[1],  *up_bs = cp[2],  *up_Wd = cp[3],  *up_bd = cp[4],  *up_attn = cp[5];
  const bf16* L_Ws    = cp[6],  *L_bs  = cp[7],  *L_Wd  = cp[8],  *L_bd  = cp[9],  *L_attn  = cp[10];
  const bf16* ff_ln_g = cp[11], *ff_ln_b = cp[12], *ff_W1 = cp[13], *ff_b1 = cp[14];
  const bf16* ff_W2   = cp[15], *ff_b2 = cp[16], *ff_W3 = cp[17], *ff_b3 = cp[18];
  const bf16* seq_Ws  = cp[19], *seq_bs = cp[20], *seq_Wd = cp[21], *seq_bd = cp[22], *seq_attn = cp[23];
  const bf16* fs_ln_g = cp[24], *fs_ln_b = cp[25], *fs_W1 = cp[26], *fs_b1 = cp[27];
  const bf16* fs_W2   = cp[28], *fs_b2 = cp[29];
  const bf16* gate_W  = cp[30], *gate_b = cp[31];

  bf16* X  = (bf16*)take((size_t)NN*128*2);
  bf16* A  = (bf16*)take((size_t)NN*1024*2);   // el / ff output / final y2
  bf16* Bf = (bf16*)take((size_t)NN*1024*2);   // er / aggregation output
  bf16* T  = (bf16*)take((size_t)NN*256*2);    // ff hidden
  (void)ws_size; (void)n_in; (void)out_size;

  // ---- dtype detect + convert params ----
  k_detect<<<1, 256, 0, stream>>>((const unsigned short*)d_in[0], flag);
  k_conv_all<<<dim3((maxn+255)/256, 32), 256, 0, stream>>>(ca, flag);

  // ---- CSR build ----
  k_zero2 <<<(NN+255)/256, 256, 0, stream>>>(deg, cursor, NN);
  k_hist  <<<(NE_TOT+255)/256, 256, 0, stream>>>(dst, deg, NE_TOT);
  k_scan  <<<1, 256, 0, stream>>>(deg, off);
  k_scatter<<<(NE_TOT+255)/256, 256, 0, stream>>>(src, dst, off, cursor, csr_src, NE_TOT);
  k_fill_dst<<<(NN+255)/256, 256, 0, stream>>>(off, csr_dst);

  // ---- attn_up (H=1): el->A, er->Bf, out->X ----
  k_up    <<<NN, 128, 0, stream>>>(cfeats, up_Ws, up_bs, up_Wd, up_bd, A, Bf);
  k_logits<<<NE_TOT/4, 256, 0, stream>>>(A, Bf, up_attn, csr_src, csr_dst, logits, 1);
  k_soft  <<<(NN+255)/256, 256, 0, stream>>>(off, logits, 1);
  k_aggr  <<<NN/4, 256, 0, stream>>>(off, csr_src, logits, A, X, 1);

  // ---- middle layers (H=2) ----
  for(int l=0; l<2; l++){
    k_gemm<0><<<dim3(4, NN/64), 256, 0, stream>>>(X, 128, L_Ws + l*32768, L_bs + l*256, A,  256, NN, 128, 256);
    k_gemm<0><<<dim3(4, NN/64), 256, 0, stream>>>(X, 128, L_Wd + l*32768, L_bd + l*256, Bf, 256, NN, 128, 256);
    k_logits<<<NE_TOT/4, 256, 0, stream>>>(A, Bf, L_attn + l*256, csr_src, csr_dst, logits, 2);
    k_soft  <<<(NN*2+255)/256, 256, 0, stream>>>(off, logits, 2);
    k_aggr  <<<NN*2/4, 256, 0, stream>>>(off, csr_src, logits, A, Bf, 2);   // er dead -> Bf
    k_ln    <<<NN*2/4, 256, 0, stream>>>(Bf, ff_ln_g + l*128, ff_ln_b + l*128, NN*2);
    for(int h=0; h<2; h++){
      k_gemm<1><<<dim3(4, NN/64), 256, 0, stream>>>(Bf + h*128, 256, ff_W1 + l*32768, ff_b1 + l*256, T, 256, NN, 128, 256);
      k_gemm<0><<<dim3(2, NN/64), 256, 0, stream>>>(T, 256, ff_W2 + l*32768, ff_b2 + l*128, A + h*128, 256, NN, 256, 128);
    }
    k_gemm<0><<<dim3(2, NN/64), 256, 0, stream>>>(A, 256, ff_W3 + l*32768, ff_b3 + l*128, X, 128, NN, 256, 128);
  }

  // ---- attn_seq (H=8) ----
  k_gemm<0><<<dim3(16, NN/64), 256, 0, stream>>>(X, 128, seq_Ws, seq_bs, A,  1024, NN, 128, 1024);
  k_gemm<0><<<dim3(16, NN/64), 256, 0, stream>>>(X, 128, seq_Wd, seq_bd, Bf, 1024, NN, 128, 1024);
  k_logits<<<NE_TOT/4, 256, 0, stream>>>(A, Bf, seq_attn, csr_src, csr_dst, logits, 8);
  k_soft  <<<(NN*8+255)/256, 256, 0, stream>>>(off, logits, 8);
  k_aggr  <<<NN*8/4, 256, 0, stream>>>(off, csr_src, logits, A, Bf, 8);     // er dead -> Bf
  k_ln    <<<NN*8/4, 256, 0, stream>>>(Bf, fs_ln_g, fs_ln_b, NN*8);
  for(int h=0; h<8; h++){
    k_gemm<1><<<dim3(4, NN/64), 256, 0, stream>>>(Bf + h*128, 1024, fs_W1, fs_b1, T, 256, NN, 128, 256);
    k_gemm<0><<<dim3(2, NN/64), 256, 0, stream>>>(T, 256, fs_W2, fs_b2, A + h*128, 1024, NN, 256, 128);
  }

  // ---- gate + pooling + tanh ----
  k_gate<<<NN/4, 256, 0, stream>>>(A, gate_W, gate_b, gate);
  k_pool<<<NB, 256, 0, stream>>>(gate, A, d_out, flag);
}

// Round 3
// 654.085 us; speedup vs baseline: 2.5303x; 2.5303x over previous
//
#include <hip/hip_runtime.h>
#include <hip/hip_bf16.h>

typedef __hip_bfloat16 bf16;
typedef __attribute__((ext_vector_type(8))) short short8;
typedef __attribute__((ext_vector_type(4))) float f32x4;

#define NN 16384
#define NB 64
#define NE_TOT (NN*8 + NN)
#define CW 128

__device__ __forceinline__ float b2f(bf16 x){ return __bfloat162float(x); }
__device__ __forceinline__ bf16  f2b(float x){ return __float2bfloat16(x); }
__device__ __forceinline__ float lrelu(float x){ return x > 0.f ? x : 0.2f*x; }
__device__ __forceinline__ float gelu_f(float x){ return 0.5f*x*(1.f + erff(x*0.70710678118654752f)); }
__device__ __forceinline__ float us2f(unsigned int u){ return __uint_as_float(u << 16); }
__device__ __forceinline__ unsigned short f2us(float x){ return __builtin_bit_cast(unsigned short, f2b(x)); }

// ---------------- dtype detect (one-hot feats: 0x3F80 at even u16 index iff bf16) ----------------
__global__ void k_detect(const unsigned short* __restrict__ f, int* __restrict__ flag){
  __shared__ int cnt;
  if(threadIdx.x == 0) cnt = 0;
  __syncthreads();
  int c = 0;
  for(int i = threadIdx.x; i < 2048; i += 256)
    if(f[2*i] == 0x3F80) c++;
  atomicAdd(&cnt, c);
  __syncthreads();
  if(threadIdx.x == 0) *flag = (cnt > 0) ? 0 : 1;   // 0 = bf16 inputs, 1 = f32 inputs
}

// ---------------- convert all float params to bf16; optionally transpose [L][K][J]->[L][J][K] ----------------
struct ConvArgs { const void* in[32]; bf16* out[32]; int n[32]; int tk[32]; int tj[32]; };
__global__ __launch_bounds__(256) void k_conv_all(ConvArgs a, const int* __restrict__ flag){
  int which = blockIdx.y;
  int t = blockIdx.x*256 + threadIdx.x;
  int n = a.n[which];
  if(t >= n) return;
  float v = (*flag) ? ((const float*)a.in[which])[t] : b2f(((const bf16*)a.in[which])[t]);
  int tj = a.tj[which];
  if(tj == 0){ a.out[which][t] = f2b(v); return; }
  int tk = a.tk[which], kj = tk*tj;
  int l = t / kj, r = t - l*kj;
  int k = r / tj, j = r - k*tj;
  a.out[which][l*kj + j*tk + k] = f2b(v);
}

// ---------------- CSR build (by dst) ----------------
__global__ void k_zero2(int* __restrict__ a, int* __restrict__ b, int n){
  int i = blockIdx.x*blockDim.x + threadIdx.x;
  if(i < n){ a[i] = 0; b[i] = 0; }
}
__global__ void k_hist(const int* __restrict__ dst, int* __restrict__ deg, int ne){
  int e = blockIdx.x*blockDim.x + threadIdx.x;
  if(e < ne) atomicAdd(&deg[dst[e]], 1);
}
__global__ void k_scan(const int* __restrict__ deg, int* __restrict__ off){
  __shared__ int s[256];
  int t = threadIdx.x;
  const int chunk = NN/256;
  int base = t*chunk;
  int sum = 0;
  for(int i=0;i<chunk;i++) sum += deg[base+i];
  s[t] = sum; __syncthreads();
  for(int o=1;o<256;o<<=1){
    int v = (t >= o) ? s[t-o] : 0;
    __syncthreads();
    s[t] += v;
    __syncthreads();
  }
  int run = (t == 0) ? 0 : s[t-1];
  for(int i=0;i<chunk;i++){ off[base+i] = run; run += deg[base+i]; }
  if(t == 255) off[NN] = run;
}
__global__ void k_scatter(const int* __restrict__ src, const int* __restrict__ dst,
                          const int* __restrict__ off, int* __restrict__ cursor,
                          int* __restrict__ csr_src, int ne){
  int e = blockIdx.x*blockDim.x + threadIdx.x;
  if(e < ne){
    int d = dst[e];
    int p = off[d] + atomicAdd(&cursor[d], 1);
    csr_src[p] = src[e];
  }
}

// ---------------- up projection (K=8, one block/node) ----------------
__global__ __launch_bounds__(128) void k_up(const bf16* __restrict__ feats,
    const bf16* __restrict__ Ws, const bf16* __restrict__ bs,
    const bf16* __restrict__ Wd, const bf16* __restrict__ bd,
    bf16* __restrict__ el, bf16* __restrict__ er){
  int n = blockIdx.x, c = threadIdx.x;
  __shared__ float f[8];
  if(c < 8) f[c] = b2f(feats[n*8 + c]);
  __syncthreads();
  float a = b2f(bs[c]), b = b2f(bd[c]);
  #pragma unroll
  for(int k=0;k<8;k++){
    float fv = f[k];
    a += fv*b2f(Ws[k*CW + c]);
    b += fv*b2f(Wd[k*CW + c]);
  }
  el[(size_t)n*CW + c] = f2b(a);
  er[(size_t)n*CW + c] = f2b(b);
}

// ---------------- MFMA GEMM: C[M,J] = act(A[M,K] @ W[K,J] + bias), W given TRANSPOSED [J][K] ----
// BM=64, BN=128, BK=32; block = 128 threads (2 waves, each 64x64). K,J mult of 32/128; M mult of 64.
template<int ACT>
__global__ __launch_bounds__(128) void k_mm(const bf16* __restrict__ A,
    const bf16* __restrict__ WT, const bf16* __restrict__ bias,
    bf16* __restrict__ C, int M, int K, int J){
  __shared__ short As[64][40];
  __shared__ short Bs[128][40];
  int tid = threadIdx.x;
  int w = tid >> 6, lane = tid & 63;
  int l15 = lane & 15, q = lane >> 4;
  int bm = blockIdx.y*64, bn = blockIdx.x*128;
  f32x4 acc[4][4];
  #pragma unroll
  for(int i=0;i<4;i++)
    #pragma unroll
    for(int j=0;j<4;j++) acc[i][j] = (f32x4)0.f;

  int r0 = tid >> 2, qd = tid & 3;
  for(int kt=0; kt<K; kt+=32){
    #pragma unroll
    for(int it=0; it<2; it++){
      int r = r0 + it*32;
      *(int4*)&As[r][qd*8] = *(const int4*)&A[(size_t)(bm + r)*K + kt + qd*8];
    }
    #pragma unroll
    for(int it=0; it<4; it++){
      int r = r0 + it*32;
      *(int4*)&Bs[r][qd*8] = *(const int4*)&WT[(size_t)(bn + r)*K + kt + qd*8];
    }
    __syncthreads();
    short8 af[4], bfr[4];
    #pragma unroll
    for(int i=0;i<4;i++) af[i]  = *(short8*)&As[i*16 + l15][q*8];
    #pragma unroll
    for(int j=0;j<4;j++) bfr[j] = *(short8*)&Bs[w*64 + j*16 + l15][q*8];
    #pragma unroll
    for(int i=0;i<4;i++)
      #pragma unroll
      for(int j=0;j<4;j++)
        acc[i][j] = __builtin_amdgcn_mfma_f32_16x16x32_bf16(af[i], bfr[j], acc[i][j], 0, 0, 0);
    __syncthreads();
  }
  #pragma unroll
  for(int j=0;j<4;j++){
    int n = bn + w*64 + j*16 + l15;
    float bv = b2f(bias[n]);
    #pragma unroll
    for(int i=0;i<4;i++){
      int mrow = bm + i*16 + q*4;
      #pragma unroll
      for(int r=0;r<4;r++){
        float v = acc[i][j][r] + bv;
        if(ACT == 1) v = gelu_f(v);
        C[(size_t)(mrow + r)*J + n] = f2b(v);
      }
    }
  }
}

// ---------------- vectorized bf16 row helpers ----------------
template<int E>
__device__ __forceinline__ void load_row(const bf16* p, float* f){
  if constexpr (E == 2){
    unsigned int v = *(const unsigned int*)p;
    f[0] = us2f(v & 0xffffu); f[1] = __uint_as_float(v & 0xffff0000u);
  } else if constexpr (E == 4){
    uint2 v = *(const uint2*)p;
    f[0] = us2f(v.x & 0xffffu); f[1] = __uint_as_float(v.x & 0xffff0000u);
    f[2] = us2f(v.y & 0xffffu); f[3] = __uint_as_float(v.y & 0xffff0000u);
  } else {
    uint4 a = *(const uint4*)p;
    uint4 b = *(const uint4*)(p + 8);
    unsigned int vs[8] = {a.x,a.y,a.z,a.w,b.x,b.y,b.z,b.w};
    #pragma unroll
    for(int i=0;i<8;i++){
      f[2*i]   = us2f(vs[i] & 0xffffu);
      f[2*i+1] = __uint_as_float(vs[i] & 0xffff0000u);
    }
  }
}
template<int E>
__device__ __forceinline__ void store_row(bf16* p, const float* f){
  unsigned int vs[E/2];
  #pragma unroll
  for(int i=0;i<E/2;i++)
    vs[i] = (unsigned int)f2us(f[2*i]) | ((unsigned int)f2us(f[2*i+1]) << 16);
  if constexpr (E == 2){ *(unsigned int*)p = vs[0]; }
  else if constexpr (E == 4){ *(uint2*)p = make_uint2(vs[0], vs[1]); }
  else {
    *(uint4*)p       = make_uint4(vs[0], vs[1], vs[2], vs[3]);
    *(uint4*)(p + 8) = make_uint4(vs[4], vs[5], vs[6], vs[7]);
  }
}

// ---------------- fused GATv2 edge stage: one wave per dst node, all heads ----------------
// er row streamed once/node; el rows gathered twice (logits pass + aggregate pass).
// Optional fused LayerNorm (per head, over 128 channels).
template<int H, bool LNF>
__global__ __launch_bounds__(256) void k_gat(const int* __restrict__ off, const int* __restrict__ csr_src,
    const bf16* __restrict__ el, const bf16* __restrict__ er, const bf16* __restrict__ attn,
    const bf16* __restrict__ lng, const bf16* __restrict__ lnb, bf16* __restrict__ out){
  constexpr int EPL = 2*H;     // bf16 elements per lane
  constexpr int G   = 64/H;    // lanes per head
  constexpr int MAXD = 64;
  __shared__ float lgs[4][MAXD][H];
  int w = threadIdx.x >> 6, lane = threadIdx.x & 63;
  int n = blockIdx.x*4 + w;
  const int RS = H*CW;
  int hid = lane / G;

  float ef[EPL], af[EPL];
  load_row<EPL>(er   + (size_t)n*RS + lane*EPL, ef);
  load_row<EPL>(attn + lane*EPL, af);

  int p0 = off[n], p1 = off[n+1];
  if(p1 - p0 > MAXD) p1 = p0 + MAXD;

  // pass 1: logits -> LDS
  for(int p = p0; p < p1; p++){
    int s = csr_src[p];
    float xf[EPL];
    load_row<EPL>(el + (size_t)s*RS + lane*EPL, xf);
    float part = 0.f;
    #pragma unroll
    for(int e=0;e<EPL;e++) part += af[e]*lrelu(xf[e] + ef[e]);
    #pragma unroll
    for(int o=G/2; o; o>>=1) part += __shfl_xor(part, o, 64);
    if((lane & (G-1)) == 0) lgs[w][p - p0][hid] = part;
  }
  __threadfence_block();

  // softmax stats (per head, in-register)
  int deg = p1 - p0;
  float m = -1e30f;
  for(int p=0;p<deg;p++) m = fmaxf(m, lgs[w][p][hid]);
  float z = 0.f;
  for(int p=0;p<deg;p++) z += expf(lgs[w][p][hid] - m);
  float rz = 1.f/z;

  // pass 2: weighted aggregate
  float acc[EPL];
  #pragma unroll
  for(int e=0;e<EPL;e++) acc[e] = 0.f;
  for(int p = p0; p < p1; p++){
    int s = csr_src[p];
    float c = expf(lgs[w][p - p0][hid] - m)*rz;
    float xf[EPL];
    load_row<EPL>(el + (size_t)s*RS + lane*EPL, xf);
    #pragma unroll
    for(int e=0;e<EPL;e++) acc[e] += c*xf[e];
  }

  if constexpr (LNF){
    float sl = 0.f;
    #pragma unroll
    for(int e=0;e<EPL;e++) sl += acc[e];
    #pragma unroll
    for(int o=G/2; o; o>>=1) sl += __shfl_xor(sl, o, 64);
    float mu = sl*(1.f/128.f);
    float qs = 0.f;
    #pragma unroll
    for(int e=0;e<EPL;e++){ float d = acc[e] - mu; qs += d*d; }
    #pragma unroll
    for(int o=G/2; o; o>>=1) qs += __shfl_xor(qs, o, 64);
    float r = rsqrtf(qs*(1.f/128.f) + 1e-5f);
    int cbase = (lane & (G-1))*EPL;
    #pragma unroll
    for(int e=0;e<EPL;e++)
      acc[e] = (acc[e] - mu)*r*b2f(lng[cbase + e]) + b2f(lnb[cbase + e]);
  }
  store_row<EPL>(out + (size_t)n*RS + lane*EPL, acc);
}

// ---------------- gate: one wave per node, dot over 1024 ----------------
__global__ __launch_bounds__(256) void k_gate(const bf16* __restrict__ y2, const bf16* __restrict__ gW,
                                              const bf16* __restrict__ gb, float* __restrict__ gate){
  int n = blockIdx.x*4 + (threadIdx.x >> 6);
  int lane = threadIdx.x & 63;
  const bf16* yr = y2 + (size_t)n*1024;
  float p = 0.f;
  #pragma unroll
  for(int j=0;j<16;j++) p += b2f(yr[lane + j*64])*b2f(gW[lane + j*64]);
  #pragma unroll
  for(int o=32;o;o>>=1) p += __shfl_down(p, o, 64);
  if(lane == 0) gate[n] = p + b2f(gb[0]);
}

// ---------------- gated pooling + tanh: one block per graph ----------------
__global__ __launch_bounds__(256) void k_pool(const float* __restrict__ gate, const bf16* __restrict__ y2,
                                              void* __restrict__ outv, const int* __restrict__ flag){
  int g = blockIdx.x, t = threadIdx.x;
  __shared__ float red[256];
  __shared__ float w[256];
  float gv = gate[g*256 + t];
  red[t] = gv; __syncthreads();
  for(int o=128;o;o>>=1){ if(t < o) red[t] = fmaxf(red[t], red[t+o]); __syncthreads(); }
  float m = red[0]; __syncthreads();
  float e = expf(gv - m);
  red[t] = e; __syncthreads();
  for(int o=128;o;o>>=1){ if(t < o) red[t] += red[t+o]; __syncthreads(); }
  float z = red[0]; __syncthreads();
  w[t] = e / z; __syncthreads();
  float acc[4] = {0.f,0.f,0.f,0.f};
  const bf16* base = y2 + (size_t)g*256*1024;
  for(int i=0;i<256;i++){
    float wi = w[i];
    #pragma unroll
    for(int jj=0;jj<4;jj++) acc[jj] += wi*b2f(base[(size_t)i*1024 + jj*256 + t]);
  }
  bool f32o = (*flag != 0);
  #pragma unroll
  for(int jj=0;jj<4;jj++){
    float v = tanhf(acc[jj]);
    size_t idx = (size_t)g*1024 + jj*256 + t;
    if(f32o) ((float*)outv)[idx] = v;
    else     ((bf16*)outv)[idx] = f2b(v);
  }
}

extern "C" void kernel_launch(void* const* d_in, const int* in_sizes, int n_in,
                              void* d_out, int out_size, void* d_ws, size_t ws_size,
                              hipStream_t stream){
  const int* src = (const int*)d_in[1];
  const int* dst = (const int*)d_in[2];

  char* wsb = (char*)d_ws;
  size_t o = 0;
  auto take = [&](size_t bytes)->char*{
    char* p = wsb + o; o = (o + bytes + 255) & ~(size_t)255; return p;
  };
  int*   flag  = (int*)take(4);
  float* gate  = (float*)take((size_t)NN*sizeof(float));
  int* deg     = (int*)take((size_t)NN*4);
  int* cursor  = (int*)take((size_t)NN*4);
  int* off     = (int*)take((size_t)(NN+1)*4);
  int* csr_src = (int*)take((size_t)NE_TOT*4);

  // converted (and for GEMM weights: transposed) bf16 copies of all 32 float tensors
  ConvArgs ca;
  const int fidx[32] = {0, 4,5,6,7,8, 9,10,11,12,13, 14,15,16,17,18,19,20,21,
                        22,23,24,25,26, 27,28,29,30,31,32, 33,34};
  // transpose spec per cp index: (tk, tj); 0 = plain copy
  int tks[32] = {0}, tjs[32] = {0};
  tks[6]=128;  tjs[6]=256;    // L_Ws  [2][128][256]
  tks[8]=128;  tjs[8]=256;    // L_Wd
  tks[13]=128; tjs[13]=256;   // ff_W1 [2][128][256]
  tks[15]=256; tjs[15]=128;   // ff_W2 [2][256][128]
  tks[17]=256; tjs[17]=128;   // ff_W3 [2][256][128]
  tks[19]=128; tjs[19]=1024;  // seq_Ws [128][1024]
  tks[21]=128; tjs[21]=1024;  // seq_Wd
  tks[26]=128; tjs[26]=256;   // fs_W1 [128][256]
  tks[28]=256; tjs[28]=128;   // fs_W2 [256][128]
  bf16* cp[32];
  int maxn = 0;
  for(int i=0;i<32;i++){
    int n = in_sizes[fidx[i]];
    cp[i] = (bf16*)take((size_t)n*2);
    ca.in[i] = d_in[fidx[i]]; ca.out[i] = cp[i]; ca.n[i] = n;
    ca.tk[i] = tks[i]; ca.tj[i] = tjs[i];
    if(n > maxn) maxn = n;
  }
  const bf16* cfeats  = cp[0];
  const bf16* up_Ws   = cp[1],  *up_bs = cp[2],  *up_Wd = cp[3],  *up_bd = cp[4],  *up_attn = cp[5];
  const bf16* L_WsT   = cp[6],  *L_bs  = cp[7],  *L_WdT = cp[8],  *L_bd  = cp[9],  *L_attn  = cp[10];
  const bf16* ff_ln_g = cp[11], *ff_ln_b = cp[12], *ff_W1T = cp[13], *ff_b1 = cp[14];
  const bf16* ff_W2T  = cp[15], *ff_b2 = cp[16], *ff_W3T = cp[17], *ff_b3 = cp[18];
  const bf16* seq_WsT = cp[19], *seq_bs = cp[20], *seq_WdT = cp[21], *seq_bd = cp[22], *seq_attn = cp[23];
  const bf16* fs_ln_g = cp[24], *fs_ln_b = cp[25], *fs_W1T = cp[26], *fs_b1 = cp[27];
  const bf16* fs_W2T  = cp[28], *fs_b2 = cp[29];
  const bf16* gate_W  = cp[30], *gate_b = cp[31];

  bf16* X  = (bf16*)take((size_t)NN*128*2);    // node features between blocks
  bf16* A  = (bf16*)take((size_t)NN*1024*2);   // el / FF output / final y2
  bf16* Bf = (bf16*)take((size_t)NN*1024*2);   // er / GAT+LN output
  bf16* T  = (bf16*)take((size_t)32768*256*2); // FF hidden (chunked)
  (void)ws_size; (void)n_in; (void)out_size;

  // ---- dtype detect + convert/transpose params ----
  k_detect<<<1, 256, 0, stream>>>((const unsigned short*)d_in[0], flag);
  k_conv_all<<<dim3((maxn+255)/256, 32), 256, 0, stream>>>(ca, flag);

  // ---- CSR build ----
  k_zero2 <<<(NN+255)/256, 256, 0, stream>>>(deg, cursor, NN);
  k_hist  <<<(NE_TOT+255)/256, 256, 0, stream>>>(dst, deg, NE_TOT);
  k_scan  <<<1, 256, 0, stream>>>(deg, off);
  k_scatter<<<(NE_TOT+255)/256, 256, 0, stream>>>(src, dst, off, cursor, csr_src, NE_TOT);

  // ---- attn_up (H=1): el->A, er->Bf, out->X ----
  k_up<<<NN, 128, 0, stream>>>(cfeats, up_Ws, up_bs, up_Wd, up_bd, A, Bf);
  k_gat<1,false><<<NN/4, 256, 0, stream>>>(off, csr_src, A, Bf, up_attn, nullptr, nullptr, X);

  // ---- middle layers (H=2) ----
  for(int l=0; l<2; l++){
    k_mm<0><<<dim3(2, NN/64), 128, 0, stream>>>(X, L_WsT + l*32768, L_bs + l*256, A,  NN, 128, 256);
    k_mm<0><<<dim3(2, NN/64), 128, 0, stream>>>(X, L_WdT + l*32768, L_bd + l*256, Bf, NN, 128, 256);
    k_gat<2,true><<<NN/4, 256, 0, stream>>>(off, csr_src, A, Bf, L_attn + l*256,
                                            ff_ln_g + l*128, ff_ln_b + l*128, Bf);
    // FF merged over heads: M = N*2
    k_mm<1><<<dim3(2, 2*NN/64), 128, 0, stream>>>(Bf, ff_W1T + l*32768, ff_b1 + l*256, T, 2*NN, 128, 256);
    k_mm<0><<<dim3(1, 2*NN/64), 128, 0, stream>>>(T,  ff_W2T + l*32768, ff_b2 + l*128, A, 2*NN, 256, 128);
    k_mm<0><<<dim3(1, NN/64),   128, 0, stream>>>(A,  ff_W3T + l*32768, ff_b3 + l*128, X, NN, 256, 128);
  }

  // ---- attn_seq (H=8) ----
  k_mm<0><<<dim3(8, NN/64), 128, 0, stream>>>(X, seq_WsT, seq_bs, A,  NN, 128, 1024);
  k_mm<0><<<dim3(8, NN/64), 128, 0, stream>>>(X, seq_WdT, seq_bd, Bf, NN, 128, 1024);
  k_gat<8,true><<<NN/4, 256, 0, stream>>>(off, csr_src, A, Bf, seq_attn, fs_ln_g, fs_ln_b, Bf);
  // FF merged over heads, chunked (T holds 32768 rows): 4 chunks of 2 heads
  for(int c=0; c<4; c++){
    size_t ofs = (size_t)c*32768*128;
    k_mm<1><<<dim3(2, 512), 128, 0, stream>>>(Bf + ofs, fs_W1T, fs_b1, T, 32768, 128, 256);
    k_mm<0><<<dim3(1, 512), 128, 0, stream>>>(T, fs_W2T, fs_b2, A + ofs, 32768, 256, 128);
  }

  // ---- gate + pooling + tanh ----
  k_gate<<<NN/4, 256, 0, stream>>>(A, gate_W, gate_b, gate);
  k_pool<<<NB, 256, 0, stream>>>(gate, A, d_out, flag);
}

// Round 4
// 617.615 us; speedup vs baseline: 2.6797x; 1.0591x over previous
//
#include <hip/hip_runtime.h>
#include <hip/hip_bf16.h>

typedef __hip_bfloat16 bf16;
typedef __attribute__((ext_vector_type(8))) short short8;
typedef __attribute__((ext_vector_type(4))) float f32x4;

#define NN 16384
#define NB 64
#define NE_TOT (NN*8 + NN)
#define CW 128

__device__ __forceinline__ float b2f(bf16 x){ return __bfloat162float(x); }
__device__ __forceinline__ bf16  f2b(float x){ return __float2bfloat16(x); }
__device__ __forceinline__ float lrelu(float x){ return x > 0.f ? x : 0.2f*x; }
__device__ __forceinline__ float gelu_f(float x){ return 0.5f*x*(1.f + erff(x*0.70710678118654752f)); }
__device__ __forceinline__ float us2f(unsigned int u){ return __uint_as_float(u << 16); }
__device__ __forceinline__ unsigned short f2us(float x){ return __builtin_bit_cast(unsigned short, f2b(x)); }

// async global->LDS, 16B per lane; LDS base must be wave-uniform (dest = base + lane*16)
__device__ __forceinline__ void async16(const void* g, void* l){
  __builtin_amdgcn_global_load_lds((const __attribute__((address_space(1))) void*)g,
                                   (__attribute__((address_space(3))) void*)l, 16, 0, 0);
}

// ---------------- dtype detect (one-hot feats: 0x3F80 at even u16 index iff bf16) ----------------
__global__ void k_detect(const unsigned short* __restrict__ f, int* __restrict__ flag){
  __shared__ int cnt;
  if(threadIdx.x == 0) cnt = 0;
  __syncthreads();
  int c = 0;
  for(int i = threadIdx.x; i < 2048; i += 256)
    if(f[2*i] == 0x3F80) c++;
  atomicAdd(&cnt, c);
  __syncthreads();
  if(threadIdx.x == 0) *flag = (cnt > 0) ? 0 : 1;   // 0 = bf16 inputs, 1 = f32 inputs
}

// ---------------- convert all float params to bf16; optionally transpose [L][K][J]->[L][J][K] ----------------
struct ConvArgs { const void* in[32]; bf16* out[32]; int n[32]; int tk[32]; int tj[32]; };
__global__ __launch_bounds__(256) void k_conv_all(ConvArgs a, const int* __restrict__ flag){
  int which = blockIdx.y;
  int t = blockIdx.x*256 + threadIdx.x;
  int n = a.n[which];
  if(t >= n) return;
  float v = (*flag) ? ((const float*)a.in[which])[t] : b2f(((const bf16*)a.in[which])[t]);
  int tj = a.tj[which];
  if(tj == 0){ a.out[which][t] = f2b(v); return; }
  int tk = a.tk[which], kj = tk*tj;
  int l = t / kj, r = t - l*kj;
  int k = r / tj, j = r - k*tj;
  a.out[which][l*kj + j*tk + k] = f2b(v);
}

// ---------------- CSR build (by dst) ----------------
__global__ void k_zero2(int* __restrict__ a, int* __restrict__ b, int n){
  int i = blockIdx.x*blockDim.x + threadIdx.x;
  if(i < n){ a[i] = 0; b[i] = 0; }
}
__global__ void k_hist(const int* __restrict__ dst, int* __restrict__ deg, int ne){
  int e = blockIdx.x*blockDim.x + threadIdx.x;
  if(e < ne) atomicAdd(&deg[dst[e]], 1);
}
__global__ void k_scan(const int* __restrict__ deg, int* __restrict__ off){
  __shared__ int s[256];
  int t = threadIdx.x;
  const int chunk = NN/256;
  int base = t*chunk;
  int sum = 0;
  for(int i=0;i<chunk;i++) sum += deg[base+i];
  s[t] = sum; __syncthreads();
  for(int o=1;o<256;o<<=1){
    int v = (t >= o) ? s[t-o] : 0;
    __syncthreads();
    s[t] += v;
    __syncthreads();
  }
  int run = (t == 0) ? 0 : s[t-1];
  for(int i=0;i<chunk;i++){ off[base+i] = run; run += deg[base+i]; }
  if(t == 255) off[NN] = run;
}
__global__ void k_scatter(const int* __restrict__ src, const int* __restrict__ dst,
                          const int* __restrict__ off, int* __restrict__ cursor,
                          int* __restrict__ csr_src, int ne){
  int e = blockIdx.x*blockDim.x + threadIdx.x;
  if(e < ne){
    int d = dst[e];
    int p = off[d] + atomicAdd(&cursor[d], 1);
    csr_src[p] = src[e];
  }
}

// ---------------- up projection (K=8, one block/node) ----------------
__global__ __launch_bounds__(128) void k_up(const bf16* __restrict__ feats,
    const bf16* __restrict__ Ws, const bf16* __restrict__ bs,
    const bf16* __restrict__ Wd, const bf16* __restrict__ bd,
    bf16* __restrict__ el, bf16* __restrict__ er){
  int n = blockIdx.x, c = threadIdx.x;
  __shared__ float f[8];
  if(c < 8) f[c] = b2f(feats[n*8 + c]);
  __syncthreads();
  float a = b2f(bs[c]), b = b2f(bd[c]);
  #pragma unroll
  for(int k=0;k<8;k++){
    float fv = f[k];
    a += fv*b2f(Ws[k*CW + c]);
    b += fv*b2f(Wd[k*CW + c]);
  }
  el[(size_t)n*CW + c] = f2b(a);
  er[(size_t)n*CW + c] = f2b(b);
}

// ---------------- MFMA GEMM: C[M,J] = act(A[M,K] @ W[K,J] + bias), W TRANSPOSED [J][K] ----
// BM=BN=128, BK=32; 256 threads = 4 waves in 2x2, each computing 64x64.
// M,J multiples of 128; K multiple of 32. global_load_lds width-16 staging.
template<int ACT>
__global__ __launch_bounds__(256) void k_mm(const bf16* __restrict__ A,
    const bf16* __restrict__ WT, const bf16* __restrict__ bias,
    bf16* __restrict__ C, int M, int K, int J){
  __shared__ char smem[17408];
  short* As = (short*)smem;           // [128][32]
  short* Bs = (short*)(smem + 8192);  // [128][32]
  int tid = threadIdx.x;
  int w = tid >> 6, lane = tid & 63;
  int l15 = lane & 15, q = lane >> 4;
  int wm = w >> 1, wn = w & 1;
  int bm = blockIdx.y*128, bn = blockIdx.x*128;

  f32x4 acc[4][4];
  #pragma unroll
  for(int i=0;i<4;i++)
    #pragma unroll
    for(int j=0;j<4;j++) acc[i][j] = (f32x4)0.f;

  // staging: wave w fills rows [2w*16, 2w*16+32) of both tiles; 4 lanes per row
  int r4 = lane >> 2;          // 0..15
  int c4 = (lane & 3)*8;       // elem col 0,8,16,24
  const bf16* ga0 = A  + (size_t)(bm + (2*w+0)*16 + r4)*K + c4;
  const bf16* ga1 = A  + (size_t)(bm + (2*w+1)*16 + r4)*K + c4;
  const bf16* gb0 = WT + (size_t)(bn + (2*w+0)*16 + r4)*K + c4;
  const bf16* gb1 = WT + (size_t)(bn + (2*w+1)*16 + r4)*K + c4;
  short* la0 = As + (2*w+0)*512;
  short* la1 = As + (2*w+1)*512;
  short* lb0 = Bs + (2*w+0)*512;
  short* lb1 = Bs + (2*w+1)*512;

  for(int kt=0; kt<K; kt+=32){
    async16(ga0 + kt, la0);
    async16(ga1 + kt, la1);
    async16(gb0 + kt, lb0);
    async16(gb1 + kt, lb1);
    __syncthreads();
    short8 af[4], bfr[4];
    #pragma unroll
    for(int i=0;i<4;i++) af[i]  = *(short8*)&As[(wm*64 + i*16 + l15)*32 + q*8];
    #pragma unroll
    for(int j=0;j<4;j++) bfr[j] = *(short8*)&Bs[(wn*64 + j*16 + l15)*32 + q*8];
    #pragma unroll
    for(int i=0;i<4;i++)
      #pragma unroll
      for(int j=0;j<4;j++)
        acc[i][j] = __builtin_amdgcn_mfma_f32_16x16x32_bf16(af[i], bfr[j], acc[i][j], 0, 0, 0);
    __syncthreads();
  }

  // epilogue: per-wave LDS repack (16x68 f32 scratch) -> coalesced dwordx4 stores
  float* ep = (float*)(smem + w*4352);
  int rr = lane >> 2;          // 0..15
  int cc = (lane & 3)*16;      // 0,16,32,48
  #pragma unroll
  for(int i=0;i<4;i++){
    #pragma unroll
    for(int j=0;j<4;j++){
      float bv = b2f(bias[bn + wn*64 + j*16 + l15]);
      #pragma unroll
      for(int r=0;r<4;r++){
        float v = acc[i][j][r] + bv;
        if(ACT == 1) v = gelu_f(v);
        ep[(q*4+r)*68 + j*16 + l15] = v;
      }
    }
    float4 v0 = *(float4*)&ep[rr*68 + cc];
    float4 v1 = *(float4*)&ep[rr*68 + cc + 4];
    float4 v2 = *(float4*)&ep[rr*68 + cc + 8];
    float4 v3 = *(float4*)&ep[rr*68 + cc + 12];
    float vv[16] = {v0.x,v0.y,v0.z,v0.w, v1.x,v1.y,v1.z,v1.w,
                    v2.x,v2.y,v2.z,v2.w, v3.x,v3.y,v3.z,v3.w};
    unsigned int u[8];
    #pragma unroll
    for(int k=0;k<8;k++)
      u[k] = (unsigned int)f2us(vv[2*k]) | ((unsigned int)f2us(vv[2*k+1]) << 16);
    bf16* cp = C + (size_t)(bm + wm*64 + i*16 + rr)*J + bn + wn*64 + cc;
    *(uint4*)cp       = make_uint4(u[0],u[1],u[2],u[3]);
    *(uint4*)(cp + 8) = make_uint4(u[4],u[5],u[6],u[7]);
  }
}

// ---------------- vectorized bf16 row helpers ----------------
template<int E>
__device__ __forceinline__ void load_row(const bf16* p, float* f){
  if constexpr (E == 2){
    unsigned int v = *(const unsigned int*)p;
    f[0] = us2f(v & 0xffffu); f[1] = __uint_as_float(v & 0xffff0000u);
  } else if constexpr (E == 4){
    uint2 v = *(const uint2*)p;
    f[0] = us2f(v.x & 0xffffu); f[1] = __uint_as_float(v.x & 0xffff0000u);
    f[2] = us2f(v.y & 0xffffu); f[3] = __uint_as_float(v.y & 0xffff0000u);
  } else {
    uint4 a = *(const uint4*)p;
    uint4 b = *(const uint4*)(p + 8);
    unsigned int vs[8] = {a.x,a.y,a.z,a.w,b.x,b.y,b.z,b.w};
    #pragma unroll
    for(int i=0;i<8;i++){
      f[2*i]   = us2f(vs[i] & 0xffffu);
      f[2*i+1] = __uint_as_float(vs[i] & 0xffff0000u);
    }
  }
}
template<int E>
__device__ __forceinline__ void store_row(bf16* p, const float* f){
  unsigned int vs[E/2];
  #pragma unroll
  for(int i=0;i<E/2;i++)
    vs[i] = (unsigned int)f2us(f[2*i]) | ((unsigned int)f2us(f[2*i+1]) << 16);
  if constexpr (E == 2){ *(unsigned int*)p = vs[0]; }
  else if constexpr (E == 4){ *(uint2*)p = make_uint2(vs[0], vs[1]); }
  else {
    *(uint4*)p       = make_uint4(vs[0], vs[1], vs[2], vs[3]);
    *(uint4*)(p + 8) = make_uint4(vs[4], vs[5], vs[6], vs[7]);
  }
}

// ---------------- fused GATv2 edge stage: one wave per dst node, SINGLE PASS ----------------
// online softmax: el row loaded once, used for both logit and weighted accumulation.
template<int H, bool LNF>
__global__ __launch_bounds__(256) void k_gat(const int* __restrict__ off, const int* __restrict__ csr_src,
    const bf16* __restrict__ el, const bf16* __restrict__ er, const bf16* __restrict__ attn,
    const bf16* __restrict__ lng, const bf16* __restrict__ lnb, bf16* __restrict__ out){
  constexpr int EPL = 2*H;     // bf16 elements per lane
  constexpr int G   = 64/H;    // lanes per head
  int w = threadIdx.x >> 6, lane = threadIdx.x & 63;
  int n = blockIdx.x*4 + w;
  const int RS = H*CW;

  float ef[EPL], af[EPL];
  load_row<EPL>(er   + (size_t)n*RS + lane*EPL, ef);
  load_row<EPL>(attn + lane*EPL, af);

  int p0 = off[n], p1 = off[n+1];

  float m = -1e30f, z = 0.f;
  float acc[EPL];
  #pragma unroll
  for(int e=0;e<EPL;e++) acc[e] = 0.f;

  float xf[EPL];
  int s0 = csr_src[p0];
  load_row<EPL>(el + (size_t)s0*RS + lane*EPL, xf);
  for(int p = p0; p < p1; p++){
    float xn[EPL];
    if(p + 1 < p1){
      int sn = csr_src[p+1];
      load_row<EPL>(el + (size_t)sn*RS + lane*EPL, xn);
    }
    float part = 0.f;
    #pragma unroll
    for(int e=0;e<EPL;e++) part += af[e]*lrelu(xf[e] + ef[e]);
    #pragma unroll
    for(int o=G/2; o; o>>=1) part += __shfl_xor(part, o, 64);
    float nm = fmaxf(m, part);
    float alpha = expf(m - nm);
    float c = expf(part - nm);
    z = z*alpha + c;
    #pragma unroll
    for(int e=0;e<EPL;e++) acc[e] = acc[e]*alpha + c*xf[e];
    m = nm;
    #pragma unroll
    for(int e=0;e<EPL;e++) xf[e] = xn[e];
  }
  float rz = 1.f/z;
  #pragma unroll
  for(int e=0;e<EPL;e++) acc[e] *= rz;

  if constexpr (LNF){
    float sl = 0.f;
    #pragma unroll
    for(int e=0;e<EPL;e++) sl += acc[e];
    #pragma unroll
    for(int o=G/2; o; o>>=1) sl += __shfl_xor(sl, o, 64);
    float mu = sl*(1.f/128.f);
    float qs = 0.f;
    #pragma unroll
    for(int e=0;e<EPL;e++){ float d = acc[e] - mu; qs += d*d; }
    #pragma unroll
    for(int o=G/2; o; o>>=1) qs += __shfl_xor(qs, o, 64);
    float r = rsqrtf(qs*(1.f/128.f) + 1e-5f);
    int cbase = (lane & (G-1))*EPL;
    #pragma unroll
    for(int e=0;e<EPL;e++)
      acc[e] = (acc[e] - mu)*r*b2f(lng[cbase + e]) + b2f(lnb[cbase + e]);
  }
  store_row<EPL>(out + (size_t)n*RS + lane*EPL, acc);
}

// ---------------- gate: one wave per node, dot over 1024 ----------------
__global__ __launch_bounds__(256) void k_gate(const bf16* __restrict__ y2, const bf16* __restrict__ gW,
                                              const bf16* __restrict__ gb, float* __restrict__ gate){
  int n = blockIdx.x*4 + (threadIdx.x >> 6);
  int lane = threadIdx.x & 63;
  const bf16* yr = y2 + (size_t)n*1024;
  float p = 0.f;
  #pragma unroll
  for(int j=0;j<16;j++) p += b2f(yr[lane + j*64])*b2f(gW[lane + j*64]);
  #pragma unroll
  for(int o=32;o;o>>=1) p += __shfl_down(p, o, 64);
  if(lane == 0) gate[n] = p + b2f(gb[0]);
}

// ---------------- gated pooling + tanh: one block per graph ----------------
__global__ __launch_bounds__(256) void k_pool(const float* __restrict__ gate, const bf16* __restrict__ y2,
                                              void* __restrict__ outv, const int* __restrict__ flag){
  int g = blockIdx.x, t = threadIdx.x;
  __shared__ float red[256];
  __shared__ float w[256];
  float gv = gate[g*256 + t];
  red[t] = gv; __syncthreads();
  for(int o=128;o;o>>=1){ if(t < o) red[t] = fmaxf(red[t], red[t+o]); __syncthreads(); }
  float m = red[0]; __syncthreads();
  float e = expf(gv - m);
  red[t] = e; __syncthreads();
  for(int o=128;o;o>>=1){ if(t < o) red[t] += red[t+o]; __syncthreads(); }
  float z = red[0]; __syncthreads();
  w[t] = e / z; __syncthreads();
  float acc[4] = {0.f,0.f,0.f,0.f};
  const bf16* base = y2 + (size_t)g*256*1024;
  for(int i=0;i<256;i++){
    float wi = w[i];
    #pragma unroll
    for(int jj=0;jj<4;jj++) acc[jj] += wi*b2f(base[(size_t)i*1024 + jj*256 + t]);
  }
  bool f32o = (*flag != 0);
  #pragma unroll
  for(int jj=0;jj<4;jj++){
    float v = tanhf(acc[jj]);
    size_t idx = (size_t)g*1024 + jj*256 + t;
    if(f32o) ((float*)outv)[idx] = v;
    else     ((bf16*)outv)[idx] = f2b(v);
  }
}

extern "C" void kernel_launch(void* const* d_in, const int* in_sizes, int n_in,
                              void* d_out, int out_size, void* d_ws, size_t ws_size,
                              hipStream_t stream){
  const int* src = (const int*)d_in[1];
  const int* dst = (const int*)d_in[2];

  char* wsb = (char*)d_ws;
  size_t o = 0;
  auto take = [&](size_t bytes)->char*{
    char* p = wsb + o; o = (o + bytes + 255) & ~(size_t)255; return p;
  };
  int*   flag  = (int*)take(4);
  float* gate  = (float*)take((size_t)NN*sizeof(float));
  int* deg     = (int*)take((size_t)NN*4);
  int* cursor  = (int*)take((size_t)NN*4);
  int* off     = (int*)take((size_t)(NN+1)*4);
  int* csr_src = (int*)take((size_t)NE_TOT*4);

  // converted (and for GEMM weights: transposed) bf16 copies of all 32 float tensors
  ConvArgs ca;
  const int fidx[32] = {0, 4,5,6,7,8, 9,10,11,12,13, 14,15,16,17,18,19,20,21,
                        22,23,24,25,26, 27,28,29,30,31,32, 33,34};
  int tks[32] = {0}, tjs[32] = {0};
  tks[6]=128;  tjs[6]=256;    // L_Ws  [2][128][256]
  tks[8]=128;  tjs[8]=256;    // L_Wd
  tks[13]=128; tjs[13]=256;   // ff_W1 [2][128][256]
  tks[15]=256; tjs[15]=128;   // ff_W2 [2][256][128]
  tks[17]=256; tjs[17]=128;   // ff_W3 [2][256][128]
  tks[19]=128; tjs[19]=1024;  // seq_Ws [128][1024]
  tks[21]=128; tjs[21]=1024;  // seq_Wd
  tks[26]=128; tjs[26]=256;   // fs_W1 [128][256]
  tks[28]=256; tjs[28]=128;   // fs_W2 [256][128]
  bf16* cp[32];
  int maxn = 0;
  for(int i=0;i<32;i++){
    int n = in_sizes[fidx[i]];
    cp[i] = (bf16*)take((size_t)n*2);
    ca.in[i] = d_in[fidx[i]]; ca.out[i] = cp[i]; ca.n[i] = n;
    ca.tk[i] = tks[i]; ca.tj[i] = tjs[i];
    if(n > maxn) maxn = n;
  }
  const bf16* cfeats  = cp[0];
  const bf16* up_Ws   = cp[1],  *up_bs = cp[2],  *up_Wd = cp[3],  *up_bd = cp[4],  *up_attn = cp[5];
  const bf16* L_WsT   = cp[6],  *L_bs  = cp[7],  *L_WdT = cp[8],  *L_bd  = cp[9],  *L_attn  = cp[10];
  const bf16* ff_ln_g = cp[11], *ff_ln_b = cp[12], *ff_W1T = cp[13], *ff_b1 = cp[14];
  const bf16* ff_W2T  = cp[15], *ff_b2 = cp[16], *ff_W3T = cp[17], *ff_b3 = cp[18];
  const bf16* seq_WsT = cp[19], *seq_bs = cp[20], *seq_WdT = cp[21], *seq_bd = cp[22], *seq_attn = cp[23];
  const bf16* fs_ln_g = cp[24], *fs_ln_b = cp[25], *fs_W1T = cp[26], *fs_b1 = cp[27];
  const bf16* fs_W2T  = cp[28], *fs_b2 = cp[29];
  const bf16* gate_W  = cp[30], *gate_b = cp[31];

  bf16* X  = (bf16*)take((size_t)NN*128*2);    // node features between blocks
  bf16* A  = (bf16*)take((size_t)NN*1024*2);   // el / FF output / final y2
  bf16* Bf = (bf16*)take((size_t)NN*1024*2);   // er / GAT+LN output
  bf16* T  = (bf16*)take((size_t)32768*256*2); // FF hidden (chunked)
  (void)ws_size; (void)n_in; (void)out_size;

  // ---- dtype detect + convert/transpose params ----
  k_detect<<<1, 256, 0, stream>>>((const unsigned short*)d_in[0], flag);
  k_conv_all<<<dim3((maxn+255)/256, 32), 256, 0, stream>>>(ca, flag);

  // ---- CSR build ----
  k_zero2 <<<(NN+255)/256, 256, 0, stream>>>(deg, cursor, NN);
  k_hist  <<<(NE_TOT+255)/256, 256, 0, stream>>>(dst, deg, NE_TOT);
  k_scan  <<<1, 256, 0, stream>>>(deg, off);
  k_scatter<<<(NE_TOT+255)/256, 256, 0, stream>>>(src, dst, off, cursor, csr_src, NE_TOT);

  // ---- attn_up (H=1): el->A, er->Bf, out->X ----
  k_up<<<NN, 128, 0, stream>>>(cfeats, up_Ws, up_bs, up_Wd, up_bd, A, Bf);
  k_gat<1,false><<<NN/4, 256, 0, stream>>>(off, csr_src, A, Bf, up_attn, nullptr, nullptr, X);

  // ---- middle layers (H=2) ----
  for(int l=0; l<2; l++){
    k_mm<0><<<dim3(2, 128), 256, 0, stream>>>(X, L_WsT + l*32768, L_bs + l*256, A,  NN, 128, 256);
    k_mm<0><<<dim3(2, 128), 256, 0, stream>>>(X, L_WdT + l*32768, L_bd + l*256, Bf, NN, 128, 256);
    k_gat<2,true><<<NN/4, 256, 0, stream>>>(off, csr_src, A, Bf, L_attn + l*256,
                                            ff_ln_g + l*128, ff_ln_b + l*128, Bf);
    k_mm<1><<<dim3(2, 256), 256, 0, stream>>>(Bf, ff_W1T + l*32768, ff_b1 + l*256, T, 2*NN, 128, 256);
    k_mm<0><<<dim3(1, 256), 256, 0, stream>>>(T,  ff_W2T + l*32768, ff_b2 + l*128, A, 2*NN, 256, 128);
    k_mm<0><<<dim3(1, 128), 256, 0, stream>>>(A,  ff_W3T + l*32768, ff_b3 + l*128, X, NN, 256, 128);
  }

  // ---- attn_seq (H=8) ----
  k_mm<0><<<dim3(8, 128), 256, 0, stream>>>(X, seq_WsT, seq_bs, A,  NN, 128, 1024);
  k_mm<0><<<dim3(8, 128), 256, 0, stream>>>(X, seq_WdT, seq_bd, Bf, NN, 128, 1024);
  k_gat<8,true><<<NN/4, 256, 0, stream>>>(off, csr_src, A, Bf, seq_attn, fs_ln_g, fs_ln_b, Bf);
  // FF merged over heads, chunked (T holds 32768 rows): 4 chunks of 2 heads
  for(int c=0; c<4; c++){
    size_t ofs = (size_t)c*32768*128;
    k_mm<1><<<dim3(2, 256), 256, 0, stream>>>(Bf + ofs, fs_W1T, fs_b1, T, 32768, 128, 256);
    k_mm<0><<<dim3(1, 256), 256, 0, stream>>>(T, fs_W2T, fs_b2, A + ofs, 32768, 256, 128);
  }

  // ---- gate + pooling + tanh ----
  k_gate<<<NN/4, 256, 0, stream>>>(A, gate_W, gate_b, gate);
  k_pool<<<NB, 256, 0, stream>>>(gate, A, d_out, flag);
}

// Round 5
// 514.495 us; speedup vs baseline: 3.2168x; 1.2004x over previous
//
#include <hip/hip_runtime.h>
#include <hip/hip_bf16.h>

typedef __hip_bfloat16 bf16;
typedef __attribute__((ext_vector_type(8))) short short8;
typedef __attribute__((ext_vector_type(4))) float f32x4;

#define NN 16384
#define NB 64
#define NE_TOT (NN*8 + NN)
#define CW 128

__device__ __forceinline__ float b2f(bf16 x){ return __bfloat162float(x); }
__device__ __forceinline__ bf16  f2b(float x){ return __float2bfloat16(x); }
__device__ __forceinline__ float lrelu(float x){ return fmaxf(x, 0.2f*x); }
__device__ __forceinline__ float gelu_f(float x){ return 0.5f*x*(1.f + erff(x*0.70710678118654752f)); }
__device__ __forceinline__ float us2f(unsigned int u){ return __uint_as_float(u << 16); }
__device__ __forceinline__ unsigned short f2us(float x){ return __builtin_bit_cast(unsigned short, f2b(x)); }

__device__ __forceinline__ void async16(const void* g, void* l){
  __builtin_amdgcn_global_load_lds((const __attribute__((address_space(1))) void*)g,
                                   (__attribute__((address_space(3))) void*)l, 16, 0, 0);
}

// ---------------- dtype detect (one-hot feats: 0x3F80 at even u16 index iff bf16) ----------------
__global__ void k_detect(const unsigned short* __restrict__ f, int* __restrict__ flag){
  __shared__ int cnt;
  if(threadIdx.x == 0) cnt = 0;
  __syncthreads();
  int c = 0;
  for(int i = threadIdx.x; i < 2048; i += 256)
    if(f[2*i] == 0x3F80) c++;
  atomicAdd(&cnt, c);
  __syncthreads();
  if(threadIdx.x == 0) *flag = (cnt > 0) ? 0 : 1;   // 0 = bf16 inputs, 1 = f32 inputs
}

// convert all float params to bf16; optional [L][K][J] -> out[l*ls + j*tk + k] transpose
struct ConvArgs { const void* in[32]; bf16* out[32]; int n[32]; int tk[32]; int tj[32]; int ls[32]; };
__global__ __launch_bounds__(256) void k_conv_all(ConvArgs a, const int* __restrict__ flag){
  int which = blockIdx.y;
  int t = blockIdx.x*256 + threadIdx.x;
  int n = a.n[which];
  if(t >= n) return;
  float v = (*flag) ? ((const float*)a.in[which])[t] : b2f(((const bf16*)a.in[which])[t]);
  int tj = a.tj[which];
  if(tj == 0){ a.out[which][t] = f2b(v); return; }
  int tk = a.tk[which], kj = tk*tj;
  int l = t / kj, r = t - l*kj;
  int k = r / tj, j = r - k*tj;
  a.out[which][l*a.ls[which] + j*tk + k] = f2b(v);
}

// ---------------- CSR build (by dst) ----------------
__global__ void k_zero2(int* __restrict__ a, int* __restrict__ b, int n){
  int i = blockIdx.x*blockDim.x + threadIdx.x;
  if(i < n){ a[i] = 0; b[i] = 0; }
}
__global__ void k_hist(const int* __restrict__ dst, int* __restrict__ deg, int ne){
  int e = blockIdx.x*blockDim.x + threadIdx.x;
  if(e < ne) atomicAdd(&deg[dst[e]], 1);
}
__global__ void k_scan(const int* __restrict__ deg, int* __restrict__ off){
  __shared__ int s[256];
  int t = threadIdx.x;
  const int chunk = NN/256;
  int base = t*chunk;
  int sum = 0;
  for(int i=0;i<chunk;i++) sum += deg[base+i];
  s[t] = sum; __syncthreads();
  for(int o=1;o<256;o<<=1){
    int v = (t >= o) ? s[t-o] : 0;
    __syncthreads();
    s[t] += v;
    __syncthreads();
  }
  int run = (t == 0) ? 0 : s[t-1];
  for(int i=0;i<chunk;i++){ off[base+i] = run; run += deg[base+i]; }
  if(t == 255) off[NN] = run;
}
__global__ void k_scatter(const int* __restrict__ src, const int* __restrict__ dst,
                          const int* __restrict__ off, int* __restrict__ cursor,
                          int* __restrict__ csr_src, int ne){
  int e = blockIdx.x*blockDim.x + threadIdx.x;
  if(e < ne){
    int d = dst[e];
    int p = off[d] + atomicAdd(&cursor[d], 1);
    csr_src[p] = src[e];
  }
}

// ---------------- up projection (K=8): writes fused el|er rows (stride 256) ----------------
__global__ __launch_bounds__(128) void k_up(const bf16* __restrict__ feats,
    const bf16* __restrict__ Ws, const bf16* __restrict__ bs,
    const bf16* __restrict__ Wd, const bf16* __restrict__ bd,
    bf16* __restrict__ eler){
  int n = blockIdx.x, c = threadIdx.x;
  __shared__ float f[8];
  if(c < 8) f[c] = b2f(feats[n*8 + c]);
  __syncthreads();
  float a = b2f(bs[c]), b = b2f(bd[c]);
  #pragma unroll
  for(int k=0;k<8;k++){
    float fv = f[k];
    a += fv*b2f(Ws[k*CW + c]);
    b += fv*b2f(Wd[k*CW + c]);
  }
  eler[(size_t)n*256 + c]       = f2b(a);
  eler[(size_t)n*256 + 128 + c] = f2b(b);
}

// ---------------- MFMA GEMM, BK=64, two-level row addressing ----------------
// C[r][j] = act(A[r][:] @ WT[j][:] + bias[j]); rowoff(r) = (r>>gsh)*gstr + (r&((1<<gsh)-1))*ld
// Plain layout: gsh=30, gstr=0. Grid: (J/128, M/128), 256 threads (4 waves 2x2, 64x64 each).
template<int ACT>
__global__ __launch_bounds__(256) void k_mm(
    const bf16* __restrict__ A, int gshA, int gstrA,
    const bf16* __restrict__ WT, const bf16* __restrict__ bias,
    bf16* __restrict__ C, int gshC, int gstrC,
    int K, int J){
  __shared__ char smem[32768];
  short* As = (short*)smem;            // two [128][32] sub-tiles (kh at +kh*4096 shorts)
  short* Bs = (short*)(smem + 16384);
  int tid = threadIdx.x, w = tid >> 6, lane = tid & 63;
  int l15 = lane & 15, q = lane >> 4;
  int wm = w >> 1, wn = w & 1;
  int bm = blockIdx.y*128, bn = blockIdx.x*128;

  f32x4 acc[4][4];
  #pragma unroll
  for(int i=0;i<4;i++)
    #pragma unroll
    for(int j=0;j<4;j++) acc[i][j] = (f32x4)0.f;

  // staging: wave w covers tile rows [w*32, w*32+32); chunk a = 16 rows; lane -> (row=i>>2, col=(i&3)*8)
  int srow = w*32 + (lane >> 2);
  int scol = (lane & 3)*8;
  const bf16* gA[2]; const bf16* gB[2];
  short* lA[2]; short* lB[2];
  int mskA = (1 << gshA) - 1;
  #pragma unroll
  for(int a=0;a<2;a++){
    int rowA = bm + srow + a*16;
    gA[a] = A  + (size_t)(rowA >> gshA)*(size_t)gstrA + (size_t)(rowA & mskA)*K + scol;
    gB[a] = WT + (size_t)(bn + srow + a*16)*K + scol;
    lA[a] = As + (w*32 + a*16)*32;
    lB[a] = Bs + (w*32 + a*16)*32;
  }

  for(int kt=0; kt<K; kt+=64){
    #pragma unroll
    for(int a=0;a<2;a++)
      #pragma unroll
      for(int kh=0;kh<2;kh++){
        async16(gA[a] + kt + kh*32, lA[a] + kh*4096);
        async16(gB[a] + kt + kh*32, lB[a] + kh*4096);
      }
    __syncthreads();
    #pragma unroll
    for(int kh=0;kh<2;kh++){
      short8 af[4], bfr[4];
      #pragma unroll
      for(int i=0;i<4;i++) af[i]  = *(short8*)&As[kh*4096 + (wm*64 + i*16 + l15)*32 + q*8];
      #pragma unroll
      for(int j=0;j<4;j++) bfr[j] = *(short8*)&Bs[kh*4096 + (wn*64 + j*16 + l15)*32 + q*8];
      #pragma unroll
      for(int i=0;i<4;i++)
        #pragma unroll
        for(int j=0;j<4;j++)
          acc[i][j] = __builtin_amdgcn_mfma_f32_16x16x32_bf16(af[i], bfr[j], acc[i][j], 0, 0, 0);
    }
    __syncthreads();
  }

  // epilogue: per-wave LDS repack -> coalesced dwordx4 stores
  float* ep = (float*)(smem + w*4352);
  int rr = lane >> 2;
  int cc = (lane & 3)*16;
  int mskC = (1 << gshC) - 1;
  #pragma unroll
  for(int i=0;i<4;i++){
    #pragma unroll
    for(int j=0;j<4;j++){
      float bv = b2f(bias[bn + wn*64 + j*16 + l15]);
      #pragma unroll
      for(int r=0;r<4;r++){
        float v = acc[i][j][r] + bv;
        if(ACT == 1) v = gelu_f(v);
        ep[(q*4+r)*68 + j*16 + l15] = v;
      }
    }
    float4 v0 = *(float4*)&ep[rr*68 + cc];
    float4 v1 = *(float4*)&ep[rr*68 + cc + 4];
    float4 v2 = *(float4*)&ep[rr*68 + cc + 8];
    float4 v3 = *(float4*)&ep[rr*68 + cc + 12];
    float vv[16] = {v0.x,v0.y,v0.z,v0.w, v1.x,v1.y,v1.z,v1.w,
                    v2.x,v2.y,v2.z,v2.w, v3.x,v3.y,v3.z,v3.w};
    unsigned int u[8];
    #pragma unroll
    for(int k=0;k<8;k++)
      u[k] = (unsigned int)f2us(vv[2*k]) | ((unsigned int)f2us(vv[2*k+1]) << 16);
    int row = bm + wm*64 + i*16 + rr;
    bf16* cp = C + (size_t)(row >> gshC)*(size_t)gstrC + (size_t)(row & mskC)*J + bn + wn*64 + cc;
    *(uint4*)cp       = make_uint4(u[0],u[1],u[2],u[3]);
    *(uint4*)(cp + 8) = make_uint4(u[4],u[5],u[6],u[7]);
  }
}

// ---------------- vectorized bf16 row helpers ----------------
template<int E>
__device__ __forceinline__ void load_row(const bf16* p, float* f){
  if constexpr (E == 2){
    unsigned int v = *(const unsigned int*)p;
    f[0] = us2f(v & 0xffffu); f[1] = __uint_as_float(v & 0xffff0000u);
  } else if constexpr (E == 4){
    uint2 v = *(const uint2*)p;
    f[0] = us2f(v.x & 0xffffu); f[1] = __uint_as_float(v.x & 0xffff0000u);
    f[2] = us2f(v.y & 0xffffu); f[3] = __uint_as_float(v.y & 0xffff0000u);
  } else {
    uint4 a = *(const uint4*)p;
    uint4 b = *(const uint4*)(p + 8);
    unsigned int vs[8] = {a.x,a.y,a.z,a.w,b.x,b.y,b.z,b.w};
    #pragma unroll
    for(int i=0;i<8;i++){
      f[2*i]   = us2f(vs[i] & 0xffffu);
      f[2*i+1] = __uint_as_float(vs[i] & 0xffff0000u);
    }
  }
}
template<int E>
__device__ __forceinline__ void store_row(bf16* p, const float* f){
  unsigned int vs[E/2];
  #pragma unroll
  for(int i=0;i<E/2;i++)
    vs[i] = (unsigned int)f2us(f[2*i]) | ((unsigned int)f2us(f[2*i+1]) << 16);
  if constexpr (E == 2){ *(unsigned int*)p = vs[0]; }
  else if constexpr (E == 4){ *(uint2*)p = make_uint2(vs[0], vs[1]); }
  else {
    *(uint4*)p       = make_uint4(vs[0], vs[1], vs[2], vs[3]);
    *(uint4*)(p + 8) = make_uint4(vs[4], vs[5], vs[6], vs[7]);
  }
}

// ---------------- fused GATv2: one wave/dst node, single pass, online softmax ----------------
// rs_in: element stride between node rows of el/er; rs_out: stride of out rows.
template<int H, bool LNF>
__global__ __launch_bounds__(256) void k_gat(const int* __restrict__ off, const int* __restrict__ csr_src,
    const bf16* __restrict__ el, const bf16* __restrict__ er, const bf16* __restrict__ attn,
    const bf16* __restrict__ lng, const bf16* __restrict__ lnb, bf16* __restrict__ out,
    int rs_in, int rs_out){
  constexpr int EPL = 2*H;
  constexpr int G   = 64/H;
  int w = threadIdx.x >> 6, lane = threadIdx.x & 63;
  int n = blockIdx.x*4 + w;

  float ef[EPL], af[EPL];
  load_row<EPL>(er   + (size_t)n*rs_in + lane*EPL, ef);
  load_row<EPL>(attn + lane*EPL, af);

  int p0 = off[n], p1 = off[n+1];

  float m = -1e30f, z = 0.f;
  float acc[EPL];
  #pragma unroll
  for(int e=0;e<EPL;e++) acc[e] = 0.f;

  float xf[EPL];
  int s0 = csr_src[p0];
  load_row<EPL>(el + (size_t)s0*rs_in + lane*EPL, xf);
  for(int p = p0; p < p1; p++){
    float xn[EPL];
    if(p + 1 < p1){
      int sn = csr_src[p+1];
      load_row<EPL>(el + (size_t)sn*rs_in + lane*EPL, xn);
    }
    float part = 0.f;
    #pragma unroll
    for(int e=0;e<EPL;e++) part += af[e]*lrelu(xf[e] + ef[e]);
    #pragma unroll
    for(int o=G/2; o; o>>=1) part += __shfl_xor(part, o, 64);
    float nm = fmaxf(m, part);
    float alpha = expf(m - nm);
    float c = expf(part - nm);
    z = z*alpha + c;
    #pragma unroll
    for(int e=0;e<EPL;e++) acc[e] = acc[e]*alpha + c*xf[e];
    m = nm;
    #pragma unroll
    for(int e=0;e<EPL;e++) xf[e] = xn[e];
  }
  float rz = 1.f/z;
  #pragma unroll
  for(int e=0;e<EPL;e++) acc[e] *= rz;

  if constexpr (LNF){
    float sl = 0.f;
    #pragma unroll
    for(int e=0;e<EPL;e++) sl += acc[e];
    #pragma unroll
    for(int o=G/2; o; o>>=1) sl += __shfl_xor(sl, o, 64);
    float mu = sl*(1.f/128.f);
    float qs = 0.f;
    #pragma unroll
    for(int e=0;e<EPL;e++){ float d = acc[e] - mu; qs += d*d; }
    #pragma unroll
    for(int o=G/2; o; o>>=1) qs += __shfl_xor(qs, o, 64);
    float r = rsqrtf(qs*(1.f/128.f) + 1e-5f);
    int cbase = (lane & (G-1))*EPL;
    #pragma unroll
    for(int e=0;e<EPL;e++)
      acc[e] = (acc[e] - mu)*r*b2f(lng[cbase + e]) + b2f(lnb[cbase + e]);
  }
  store_row<EPL>(out + (size_t)n*rs_out + lane*EPL, acc);
}

// ---------------- gate: one wave per node (y2 row stride 2048) ----------------
__global__ __launch_bounds__(256) void k_gate(const bf16* __restrict__ y2, const bf16* __restrict__ gW,
                                              const bf16* __restrict__ gb, float* __restrict__ gate){
  int n = blockIdx.x*4 + (threadIdx.x >> 6);
  int lane = threadIdx.x & 63;
  const bf16* yr = y2 + (size_t)n*2048;
  float p = 0.f;
  #pragma unroll
  for(int j=0;j<16;j++) p += b2f(yr[lane + j*64])*b2f(gW[lane + j*64]);
  #pragma unroll
  for(int o=32;o;o>>=1) p += __shfl_down(p, o, 64);
  if(lane == 0) gate[n] = p + b2f(gb[0]);
}

// ---------------- pool stage 1: per-graph softmax stats (64 blocks x 64 thr) ----------------
__global__ __launch_bounds__(64) void k_pool1(const float* __restrict__ gate,
                                              float* __restrict__ gm, float* __restrict__ gz){
  int g = blockIdx.x, lane = threadIdx.x;
  float v0 = gate[g*256 + lane], v1 = gate[g*256 + 64 + lane];
  float v2 = gate[g*256 + 128 + lane], v3 = gate[g*256 + 192 + lane];
  float m = fmaxf(fmaxf(v0,v1), fmaxf(v2,v3));
  #pragma unroll
  for(int o=32;o;o>>=1) m = fmaxf(m, __shfl_xor(m, o, 64));
  float z = expf(v0-m) + expf(v1-m) + expf(v2-m) + expf(v3-m);
  #pragma unroll
  for(int o=32;o;o>>=1) z += __shfl_xor(z, o, 64);
  if(lane == 0){ gm[g] = m; gz[g] = z; }
}

// ---------------- pool stage 2: weighted sum + tanh (256 blocks: 64 graphs x 4 col-blocks) ----
__global__ __launch_bounds__(256) void k_pool2(const float* __restrict__ gate,
    const float* __restrict__ gm, const float* __restrict__ gz,
    const bf16* __restrict__ y2, void* __restrict__ outv, const int* __restrict__ flag){
  int g = blockIdx.x >> 2, cb = blockIdx.x & 3, t = threadIdx.x;
  __shared__ float aL[256];
  aL[t] = expf(gate[g*256 + t] - gm[g]) / gz[g];
  __syncthreads();
  int ch = cb*256 + t;
  float acc = 0.f;
  const bf16* base = y2 + (size_t)g*256*2048 + ch;
  for(int i=0;i<256;i++) acc += aL[i]*b2f(base[(size_t)i*2048]);
  float v = tanhf(acc);
  size_t idx = (size_t)g*1024 + ch;
  if(*flag) ((float*)outv)[idx] = v;
  else      ((bf16*)outv)[idx] = f2b(v);
}

extern "C" void kernel_launch(void* const* d_in, const int* in_sizes, int n_in,
                              void* d_out, int out_size, void* d_ws, size_t ws_size,
                              hipStream_t stream){
  const int* src = (const int*)d_in[1];
  const int* dst = (const int*)d_in[2];

  char* wsb = (char*)d_ws;
  size_t o = 0;
  auto take = [&](size_t bytes)->char*{
    char* p = wsb + o; o = (o + bytes + 255) & ~(size_t)255; return p;
  };
  int*   flag  = (int*)take(4);
  float* gate  = (float*)take((size_t)NN*4);
  float* gm    = (float*)take(64*4);
  float* gz    = (float*)take(64*4);
  int* deg     = (int*)take((size_t)NN*4);
  int* cursor  = (int*)take((size_t)NN*4);
  int* off     = (int*)take((size_t)(NN+1)*4);
  int* csr_src = (int*)take((size_t)NE_TOT*4);

  bf16* WcombL   = (bf16*)take((size_t)2*512*128*2);   // [L][512][128] (Ws|Wd)^T
  bf16* bcombL   = (bf16*)take((size_t)2*512*2);
  bf16* WcombSeq = (bf16*)take((size_t)2048*128*2);    // [2048][128] (Ws|Wd)^T
  bf16* bcombSeq = (bf16*)take((size_t)2048*2);

  // conversion spec: {cp index -> out ptr, transpose}
  ConvArgs ca;
  const int fidx[32] = {0, 4,5,6,7,8, 9,10,11,12,13, 14,15,16,17,18,19,20,21,
                        22,23,24,25,26, 27,28,29,30,31,32, 33,34};
  bf16* cp[32];
  int maxn = 0;
  for(int i=0;i<32;i++){
    int n = in_sizes[fidx[i]];
    ca.in[i] = d_in[fidx[i]]; ca.n[i] = n;
    ca.tk[i] = 0; ca.tj[i] = 0; ca.ls[i] = 0;
    cp[i] = nullptr;
    if(n > maxn) maxn = n;
  }
  auto plain = [&](int i){ cp[i] = (bf16*)take((size_t)ca.n[i]*2); ca.out[i] = cp[i]; };
  auto spec  = [&](int i, bf16* dst_, int tk, int tj, int ls){
    ca.out[i] = dst_; ca.tk[i] = tk; ca.tj[i] = tj; ca.ls[i] = ls; cp[i] = dst_; };
  auto owntr = [&](int i, int tk, int tj){
    cp[i] = (bf16*)take((size_t)ca.n[i]*2);
    ca.out[i] = cp[i]; ca.tk[i] = tk; ca.tj[i] = tj; ca.ls[i] = tk*tj; };

  plain(0);                                  // feats
  plain(1); plain(2); plain(3); plain(4); plain(5);   // up_*
  spec(6,  WcombL,          128, 256, 65536);         // L_Ws^T -> cols 0..255
  spec(7,  bcombL,          256, 1,   512);           // L_bs
  spec(8,  WcombL + 32768,  128, 256, 65536);         // L_Wd^T -> cols 256..511
  spec(9,  bcombL + 256,    256, 1,   512);           // L_bd
  plain(10); plain(11); plain(12);                    // L_attn, ff_ln_g/b
  owntr(13, 128, 256);                                // ff_W1^T [2][256][128]
  plain(14);                                          // ff_b1
  owntr(15, 256, 128); plain(16);                     // ff_W2^T, ff_b2
  owntr(17, 256, 128); plain(18);                     // ff_W3^T, ff_b3
  spec(19, WcombSeq,           128, 1024, 131072);    // seq_Ws^T
  spec(20, bcombSeq,           1024, 1,  2048);       // seq_bs
  spec(21, WcombSeq + 131072,  128, 1024, 131072);    // seq_Wd^T
  spec(22, bcombSeq + 1024,    1024, 1,  2048);       // seq_bd
  plain(23); plain(24); plain(25);                    // seq_attn, fs_ln_g/b
  owntr(26, 128, 256); plain(27);                     // fs_W1^T, fs_b1
  owntr(28, 256, 128); plain(29);                     // fs_W2^T, fs_b2
  plain(30); plain(31);                               // gate_W, gate_b

  bf16* AB = (bf16*)take((size_t)NN*2048*2);   // 67 MB: el|er interleaved (seq) / staging (L)
  bf16* X  = (bf16*)take((size_t)NN*128*2);
  size_t bigT = (size_t)131072*256*2, smallT = (size_t)32768*256*2;
  bool useBigT = (ws_size - o) >= bigT + 4096;
  bf16* T = (bf16*)take(useBigT ? bigT : smallT);

  bf16* G1 = AB + (size_t)NN*1024;             // L: GAT+LN out [2N][128]
  bf16* G2 = AB + (size_t)NN*1024 + (size_t)NN*256; // L: ff W2 out [2N][128]

  // ---- dtype detect + convert/transpose params ----
  k_detect<<<1, 256, 0, stream>>>((const unsigned short*)d_in[0], flag);
  k_conv_all<<<dim3((maxn+255)/256, 32), 256, 0, stream>>>(ca, flag);

  // ---- CSR build ----
  k_zero2 <<<(NN+255)/256, 256, 0, stream>>>(deg, cursor, NN);
  k_hist  <<<(NE_TOT+255)/256, 256, 0, stream>>>(dst, deg, NE_TOT);
  k_scan  <<<1, 256, 0, stream>>>(deg, off);
  k_scatter<<<(NE_TOT+255)/256, 256, 0, stream>>>(src, dst, off, cursor, csr_src, NE_TOT);

  // ---- attn_up (H=1): fused el|er rows (stride 256) in AB ----
  k_up<<<NN, 128, 0, stream>>>(cp[0], cp[1], cp[2], cp[3], cp[4], AB);
  k_gat<1,false><<<NN/4, 256, 0, stream>>>(off, csr_src, AB, AB + 128, cp[5],
                                           nullptr, nullptr, X, 256, 128);

  // ---- middle layers (H=2) ----
  for(int l=0; l<2; l++){
    k_mm<0><<<dim3(4, 128), 256, 0, stream>>>(X, 30, 0, WcombL + l*65536, bcombL + l*512,
                                              AB, 30, 0, 128, 512);
    k_gat<2,true><<<NN/4, 256, 0, stream>>>(off, csr_src, AB, AB + 256, cp[10] + l*256,
                                            cp[11] + l*128, cp[12] + l*128, G1, 512, 256);
    k_mm<1><<<dim3(2, 256), 256, 0, stream>>>(G1, 30, 0, cp[13] + l*32768, cp[14] + l*256,
                                              T, 30, 0, 128, 256);
    k_mm<0><<<dim3(1, 256), 256, 0, stream>>>(T, 30, 0, cp[15] + l*32768, cp[16] + l*128,
                                              G2, 30, 0, 256, 128);
    k_mm<0><<<dim3(1, 128), 256, 0, stream>>>(G2, 30, 0, cp[17] + l*32768, cp[18] + l*128,
                                              X, 30, 0, 256, 128);
  }

  // ---- attn_seq (H=8): fused el|er GEMM (J=2048), GAT writes into er region ----
  k_mm<0><<<dim3(16, 128), 256, 0, stream>>>(X, 30, 0, WcombSeq, bcombSeq, AB, 30, 0, 128, 2048);
  k_gat<8,true><<<NN/4, 256, 0, stream>>>(off, csr_src, AB, AB + 1024, cp[23],
                                          cp[24], cp[25], AB + 1024, 2048, 2048);
  // fs FF: rows in groups of 8 (per node), group stride 2048
  if(useBigT){
    k_mm<1><<<dim3(2, 1024), 256, 0, stream>>>(AB + 1024, 3, 2048, cp[26], cp[27], T, 30, 0, 128, 256);
    k_mm<0><<<dim3(1, 1024), 256, 0, stream>>>(T, 30, 0, cp[28], cp[29], AB, 3, 2048, 256, 128);
  } else {
    for(int c=0; c<4; c++){
      bf16* base = AB + (size_t)c*4096*2048;
      k_mm<1><<<dim3(2, 256), 256, 0, stream>>>(base + 1024, 3, 2048, cp[26], cp[27], T, 30, 0, 128, 256);
      k_mm<0><<<dim3(1, 256), 256, 0, stream>>>(T, 30, 0, cp[28], cp[29], base, 3, 2048, 256, 128);
    }
  }

  // ---- gate + pooling + tanh ----
  k_gate <<<NN/4, 256, 0, stream>>>(AB, cp[30], cp[31], gate);
  k_pool1<<<NB, 64, 0, stream>>>(gate, gm, gz);
  k_pool2<<<NB*4, 256, 0, stream>>>(gate, gm, gz, AB, d_out, flag);
  (void)n_in; (void)out_size;
}